// Round 11
// baseline (175.808 us; speedup 1.0000x reference)
//
#include <hip/hip_runtime.h>
#include <hip/hip_bf16.h>

using f32x4 = __attribute__((ext_vector_type(4))) float;
using s16x8 = __attribute__((ext_vector_type(8))) short;

constexpr int KDIM = 768;
constexpr int NDIM = 768;
constexpr int NKT = KDIM / 32;   // 24 k-tiles (MFMA K=32)
constexpr int N16 = NDIM / 16;   // 48 n16 tiles
constexpr int NBB = NDIM / 128;  // 6 col-blocks (block = 64 rows x 128 cols)

__device__ __forceinline__ unsigned short f2bf(float f) {
    __bf16 h = (__bf16)f;        // pairs lower to v_cvt_pk_bf16_f32
    return __builtin_bit_cast(unsigned short, h);
}

__device__ __forceinline__ short sgnbf(float w) {
    unsigned u = __builtin_bit_cast(unsigned, w);
    return (w != 0.f) ? (short)(unsigned short)(0x3F80u | ((u >> 16) & 0x8000u))
                      : (short)0;
}

__device__ __forceinline__ s16x8 cvt8(float4 u, float4 v) {
    s16x8 c;
    c[0] = (short)f2bf(u.x); c[1] = (short)f2bf(u.y);
    c[2] = (short)f2bf(u.z); c[3] = (short)f2bf(u.w);
    c[4] = (short)f2bf(v.x); c[5] = (short)f2bf(v.y);
    c[6] = (short)f2bf(v.z); c[7] = (short)f2bf(v.w);
    return c;
}

// Wf[((n16*NKT + kt)*64 + lane)*8 + j] = sign(W[n16*16+(lane&15)][kt*32+(lane>>4)*8+j])
__global__ void binarize_w(const float* __restrict__ W, unsigned short* __restrict__ Wf) {
    const int g = blockIdx.x * 256 + threadIdx.x;   // 48*24*64 = 73728 threads
    const int lane = g & 63;
    const int grp  = g >> 6;
    const int kt   = grp % NKT;
    const int n16  = grp / NKT;
    const int col  = n16 * 16 + (lane & 15);
    const int k0   = kt * 32 + (lane >> 4) * 8;
    const float* src = W + (size_t)col * KDIM + k0;
    s16x8 r;
    #pragma unroll
    for (int j = 0; j < 8; ++j) r[j] = sgnbf(src[j]);
    *(s16x8*)(Wf + (size_t)g * 8) = r;
}

// No-LDS, no-barrier GEMM: each wave owns a 32x64 output tile, depth-2
// register prefetch, latency hidden purely by occupancy (TLP).
template<bool PRE>
__global__ __launch_bounds__(256, 4)
void binlin_mfma(const float* __restrict__ X, const float* __restrict__ W,
                 const unsigned short* __restrict__ Wf, float* __restrict__ Out) {
    const int bid = blockIdx.x;
    const int cpx = gridDim.x >> 3;                 // 3072 % 8 == 0 -> bijective
    const int swz = (bid & 7) * cpx + (bid >> 3);   // same-XCD chunks; bn fastest
    const int bm = swz / NBB;                       // 64-row group (512 of them)
    const int bn = swz - bm * NBB;                  // 128-col group (6 of them)

    const int t    = threadIdx.x;
    const int lane = t & 63;
    const int wid  = t >> 6;          // 4 waves: 2 (wr, rows) x 2 (wc, cols)
    const int wr   = wid >> 1;
    const int wc   = wid & 1;
    const int rowbase = bm * 64 + wr * 32;
    const int n16g    = bn * 8 + wc * 4;    // wave's first n16 tile

    // A: lane reads rows rowbase + (lane&15) (+16 for m=1), k-chunk (lane>>4)*8
    const float* Ab = X + (size_t)(rowbase + (lane & 15)) * KDIM + (lane >> 4) * 8;

    auto loadA = [&](int kt, float4 a[2][2]) {
        const float* p = Ab + kt * 32;
        a[0][0] = *(const float4*)p;
        a[0][1] = *(const float4*)(p + 4);
        a[1][0] = *(const float4*)(p + (size_t)16 * KDIM);
        a[1][1] = *(const float4*)(p + (size_t)16 * KDIM + 4);
    };
    auto loadB = [&](int kt, s16x8 b[4]) {
        if constexpr (PRE) {
            const unsigned short* q =
                Wf + ((size_t)(n16g * NKT + kt) * 64 + lane) * 8;
            #pragma unroll
            for (int n = 0; n < 4; ++n)
                b[n] = *(const s16x8*)(q + (size_t)n * NKT * 64 * 8);
        } else {
            #pragma unroll
            for (int n = 0; n < 4; ++n) {
                const int col = (n16g + n) * 16 + (lane & 15);
                const int k0  = kt * 32 + (lane >> 4) * 8;
                const float* wp = W + (size_t)col * KDIM + k0;
                float4 u = *(const float4*)wp;
                float4 v = *(const float4*)(wp + 4);
                s16x8 c;
                c[0] = sgnbf(u.x); c[1] = sgnbf(u.y); c[2] = sgnbf(u.z); c[3] = sgnbf(u.w);
                c[4] = sgnbf(v.x); c[5] = sgnbf(v.y); c[6] = sgnbf(v.z); c[7] = sgnbf(v.w);
                b[n] = c;
            }
        }
    };

    f32x4 acc[2][4] = {};
    float4 A0[2][2], A1[2][2];
    s16x8  B0[4], B1[4];

    // depth-2 prologue: two tiles in flight
    loadA(0, A0); loadB(0, B0);
    loadA(1, A1); loadB(1, B1);

    #pragma unroll
    for (int kt = 0; kt < NKT; ++kt) {
        float4 (&Ac)[2][2] = (kt & 1) ? A1 : A0;
        s16x8  (&Bc)[4]    = (kt & 1) ? B1 : B0;

        // convert current A (waits on loads issued 2 iters ago; counted vmcnt)
        s16x8 af[2];
        af[0] = cvt8(Ac[0][0], Ac[0][1]);
        af[1] = cvt8(Ac[1][0], Ac[1][1]);

        // Ac regs now dead -> reload with tile kt+2 (stays in flight ~2 iters)
        if (kt + 2 < NKT) loadA(kt + 2, Ac);

        #pragma unroll
        for (int m = 0; m < 2; ++m)
            #pragma unroll
            for (int n = 0; n < 4; ++n)
                acc[m][n] = __builtin_amdgcn_mfma_f32_16x16x32_bf16(
                    af[m], Bc[n], acc[m][n], 0, 0, 0);

        // Bc consumed by the MFMAs above -> reload with tile kt+2
        if (kt + 2 < NKT) loadB(kt + 2, Bc);
    }

    // epilogue: C/D layout col = lane&15, row = (lane>>4)*4 + reg
    float* Ob = Out + (size_t)rowbase * NDIM + bn * 128 + wc * 64;
    const int lr = lane & 15;
    #pragma unroll
    for (int m = 0; m < 2; ++m) {
        const int row0 = m * 16 + (lane >> 4) * 4;
        #pragma unroll
        for (int n = 0; n < 4; ++n) {
            const int col = n * 16 + lr;
            #pragma unroll
            for (int rr = 0; rr < 4; ++rr)
                Ob[(size_t)(row0 + rr) * NDIM + col] = acc[m][n][rr];
        }
    }
}

extern "C" void kernel_launch(void* const* d_in, const int* in_sizes, int n_in,
                              void* d_out, int out_size, void* d_ws, size_t ws_size,
                              hipStream_t stream) {
    const float* X = (const float*)d_in[0];
    const float* W = (const float*)d_in[1];
    float* Out = (float*)d_out;
    const int M = in_sizes[0] / KDIM;                  // 32768
    const int grid = (M / 64) * NBB;                   // 512 * 6 = 3072
    const size_t need = (size_t)NDIM * KDIM * sizeof(unsigned short);  // 1.125 MB

    if (ws_size >= need) {
        unsigned short* Wf = (unsigned short*)d_ws;
        binarize_w<<<(N16 * NKT * 64) / 256, 256, 0, stream>>>(W, Wf);
        binlin_mfma<true><<<grid, 256, 0, stream>>>(X, W, Wf, Out);
    } else {
        binlin_mfma<false><<<grid, 256, 0, stream>>>(X, W, nullptr, Out);
    }
}

// Round 12
// 67.956 us; speedup vs baseline: 2.5871x; 2.5871x over previous
//
#include <hip/hip_runtime.h>
#include <hip/hip_bf16.h>

using f32x4 = __attribute__((ext_vector_type(4))) float;
using s16x8 = __attribute__((ext_vector_type(8))) short;

constexpr int KDIM = 768;
constexpr int NDIM = 768;
constexpr int BM = 64;
constexpr int BN = 128;
constexpr int BK = 32;
constexpr int NBN = NDIM / BN;  // 6
constexpr int NT = KDIM / BK;   // 24 k-iterations

__device__ __forceinline__ unsigned short f2bf(float f) {
    __bf16 h = (__bf16)f;       // pairs lower to v_cvt_pk_bf16_f32
    return __builtin_bit_cast(unsigned short, h);
}

__device__ __forceinline__ short sgnbf(float w) {
    unsigned u = __builtin_bit_cast(unsigned, w);
    return (w != 0.f) ? (short)(unsigned short)(0x3F80u | ((u >> 16) & 0x8000u))
                      : (short)0;
}

__device__ __forceinline__ s16x8 cvt8(float4 u, float4 v) {
    s16x8 c;
    c[0] = (short)f2bf(u.x); c[1] = (short)f2bf(u.y);
    c[2] = (short)f2bf(u.z); c[3] = (short)f2bf(u.w);
    c[4] = (short)f2bf(v.x); c[5] = (short)f2bf(v.y);
    c[6] = (short)f2bf(v.z); c[7] = (short)f2bf(v.w);
    return c;
}

// Block-contiguous fragment-ordered W: for (kt, bn), 8 KB chunk of 512 slots.
// slot = n16l*64 + lane; element j: col = bn*128+n16l*16+(lane&15),
// k = kt*32+(lane>>4)*8+j   (identical layout to R6)
__global__ void binarize_w(const float* __restrict__ W, unsigned short* __restrict__ Wf) {
    const int g = blockIdx.x * 256 + threadIdx.x;   // 24*6*8*64 = 73728 threads
    const int lane = g & 63;
    const int grp  = g >> 6;
    const int n16l = grp & 7;
    const int bkt  = grp >> 3;
    const int bn   = bkt % NBN;
    const int kt   = bkt / NBN;
    const int col  = bn * 128 + n16l * 16 + (lane & 15);
    const int k0   = kt * 32 + (lane >> 4) * 8;
    const float* src = W + (size_t)col * KDIM + k0;
    s16x8 r;
    #pragma unroll
    for (int j = 0; j < 8; ++j) r[j] = sgnbf(src[j]);
    *(s16x8*)(Wf + (size_t)g * 8) = r;
}

// global -> LDS direct DMA, 16 B per lane. LDS dest = wave-uniform base +
// lane*16 (hardware); global src is per-lane.
__device__ __forceinline__ void gload_lds16(const void* g, void* l) {
    __builtin_amdgcn_global_load_lds(
        (const __attribute__((address_space(1))) unsigned int*)g,
        (__attribute__((address_space(3))) unsigned int*)l,
        16, 0, 0);
}

// A LDS: fragment-ordered, slot = sub16*64 + lane (256 slots x 16 B = 4 KB/buf)
// B LDS: slot = n16l*64 + lane (512 slots x 16 B = 8 KB/buf), DMA-filled linear
template<bool PRE>
__global__ __launch_bounds__(256, 6)
void binlin_mfma(const float* __restrict__ X, const float* __restrict__ W,
                 const unsigned short* __restrict__ Wf, float* __restrict__ Out) {
    __shared__ __align__(16) unsigned short As[2][256 * 8];   // 2 x 4 KB
    __shared__ __align__(16) unsigned short Bs[2][512 * 8];   // 2 x 8 KB

    const int bid = blockIdx.x;
    const int cpx = gridDim.x >> 3;                 // 3072 % 8 == 0 -> bijective
    const int swz = (bid & 7) * cpx + (bid >> 3);   // same-XCD chunks; bn fastest
    const int bm = swz / NBN;                       // 64-row tile index
    const int bn = swz - bm * NBN;

    const int t    = threadIdx.x;
    const int lane = t & 63;
    const int wid  = t >> 6;          // 4 waves: 2 (wr, 32 rows) x 2 (wc, 64 cols)
    const int wr   = wid >> 1;
    const int wc   = wid & 1;
    const int wm16 = wr * 2;          // A sub16 base (2 frags per wave)
    const int wn16 = wc * 4;          // B n16l base (4 frags per wave)

    // ---- A staging: thread t reads row r=t>>2 (of 64), k-chunk (t&3)*8;
    // adjacent lane quads cover contiguous 128 B per row (R6 coalescing).
    const int r = t >> 2;
    const int q = t & 3;
    const float* Abase = X + (size_t)(bm * BM + r) * KDIM + q * 8;
    const int sA = (r >> 4) * 64 + (r & 15) + 16 * q;   // one slot per thread

    float4 aR[2];
    auto loadA = [&](int kt) {
        const float* p = Abase + kt * BK;
        aR[0] = *(const float4*)p;
        aR[1] = *(const float4*)(p + 4);
    };
    auto writeA = [&](int buf) {
        *(s16x8*)&As[buf][(size_t)sA * 8] = cvt8(aR[0], aR[1]);
    };
    // ---- B staging via global_load_lds DMA (pure copy, fragment-ordered) ----
    // instr i of wave wid covers slots (i*4+wid)*64 .. +63 (lane-linear).
    auto stageB_dma = [&](int buf, int kt) {
        const unsigned short* chunk = Wf + (size_t)(kt * NBN + bn) * 512 * 8;
        #pragma unroll
        for (int i = 0; i < 2; ++i) {
            const int slotbase = (i * 4 + wid) * 64;
            gload_lds16(chunk + (size_t)(slotbase + lane) * 8,
                        &Bs[buf][(size_t)slotbase * 8]);
        }
    };
    // fallback (no workspace): reg-stage B with on-the-fly sign
    auto stageB_reg = [&](int buf, int kt) {
        #pragma unroll
        for (int i = 0; i < 2; ++i) {
            const int s   = t + i * 256;
            const int col = bn * 128 + (s >> 6) * 16 + (s & 15);
            const int k0  = kt * 32 + ((s >> 4) & 3) * 8;
            const float* wp = W + (size_t)col * KDIM + k0;
            float4 u = *(const float4*)wp;
            float4 v = *(const float4*)(wp + 4);
            s16x8 c;
            c[0] = sgnbf(u.x); c[1] = sgnbf(u.y); c[2] = sgnbf(u.z); c[3] = sgnbf(u.w);
            c[4] = sgnbf(v.x); c[5] = sgnbf(v.y); c[6] = sgnbf(v.z); c[7] = sgnbf(v.w);
            *(s16x8*)&Bs[buf][(size_t)s * 8] = c;
        }
    };

    f32x4 acc[2][4] = {};

    // ---- prologue ----
    loadA(0);
    writeA(0);
    if constexpr (PRE) stageB_dma(0, 0); else stageB_reg(0, 0);
    __syncthreads();

    #pragma unroll 2
    for (int kt = 0; kt < NT; ++kt) {
        const int c = kt & 1;
        const bool pf = (kt + 1 < NT);

        // issue-early: next tile's B-DMA and A-loads (hide under MFMA below)
        if (pf) {
            if constexpr (PRE) stageB_dma(c ^ 1, kt + 1);
            loadA(kt + 1);
        }

        // fragments from LDS (lane-linear ds_read_b128)
        s16x8 af[2], bf_[4];
        #pragma unroll
        for (int m = 0; m < 2; ++m)
            af[m] = *(const s16x8*)&As[c][(size_t)((wm16 + m) * 64 + lane) * 8];
        #pragma unroll
        for (int n = 0; n < 4; ++n)
            bf_[n] = *(const s16x8*)&Bs[c][(size_t)((wn16 + n) * 64 + lane) * 8];

        #pragma unroll
        for (int m = 0; m < 2; ++m)
            #pragma unroll
            for (int n = 0; n < 4; ++n)
                acc[m][n] = __builtin_amdgcn_mfma_f32_16x16x32_bf16(
                    af[m], bf_[n], acc[m][n], 0, 0, 0);

        if (pf) {
            writeA(c ^ 1);                      // waits (counted) on A-loads
            if constexpr (!PRE) stageB_reg(c ^ 1, kt + 1);
        }
        __syncthreads();                        // drains DMA + publishes buffers
    }

    // ---- epilogue: C/D layout col = lane&15, row = (lane>>4)*4 + reg ----
    float* Ob = Out + (size_t)(bm * BM + wr * 32) * NDIM + bn * BN + wc * 64;
    const int lr = lane & 15;
    #pragma unroll
    for (int m = 0; m < 2; ++m) {
        const int row0 = m * 16 + (lane >> 4) * 4;
        #pragma unroll
        for (int n = 0; n < 4; ++n) {
            const int col = n * 16 + lr;
            #pragma unroll
            for (int rr = 0; rr < 4; ++rr)
                Ob[(size_t)(row0 + rr) * NDIM + col] = acc[m][n][rr];
        }
    }
}

extern "C" void kernel_launch(void* const* d_in, const int* in_sizes, int n_in,
                              void* d_out, int out_size, void* d_ws, size_t ws_size,
                              hipStream_t stream) {
    const float* X = (const float*)d_in[0];
    const float* W = (const float*)d_in[1];
    float* Out = (float*)d_out;
    const int M = in_sizes[0] / KDIM;                  // 32768
    const int grid = (M / BM) * NBN;                   // 512 * 6 = 3072
    const size_t need = (size_t)NDIM * KDIM * sizeof(unsigned short);  // 1.125 MB

    if (ws_size >= need) {
        unsigned short* Wf = (unsigned short*)d_ws;
        binarize_w<<<(NT * NBN * 8 * 64) / 256, 256, 0, stream>>>(W, Wf);
        binlin_mfma<true><<<grid, 256, 0, stream>>>(X, W, Wf, Out);
    } else {
        binlin_mfma<false><<<grid, 256, 0, stream>>>(X, W, nullptr, Out);
    }
}

// Round 13
// 60.974 us; speedup vs baseline: 2.8833x; 1.1145x over previous
//
#include <hip/hip_runtime.h>
#include <hip/hip_bf16.h>

using f32x4 = __attribute__((ext_vector_type(4))) float;
using s16x8 = __attribute__((ext_vector_type(8))) short;

constexpr int KDIM = 768;
constexpr int NDIM = 768;
constexpr int BM = 128;
constexpr int BN = 128;
constexpr int BK = 32;
constexpr int NBN = NDIM / BN;  // 6
constexpr int NT = KDIM / BK;   // 24 k-iterations

__device__ __forceinline__ unsigned short f2bf(float f) {
    __bf16 h = (__bf16)f;       // pairs lower to v_cvt_pk_bf16_f32
    return __builtin_bit_cast(unsigned short, h);
}

__device__ __forceinline__ short sgnbf(float w) {
    unsigned u = __builtin_bit_cast(unsigned, w);
    return (w != 0.f) ? (short)(unsigned short)(0x3F80u | ((u >> 16) & 0x8000u))
                      : (short)0;
}

__device__ __forceinline__ s16x8 cvt8(float4 u, float4 v) {
    s16x8 c;
    c[0] = (short)f2bf(u.x); c[1] = (short)f2bf(u.y);
    c[2] = (short)f2bf(u.z); c[3] = (short)f2bf(u.w);
    c[4] = (short)f2bf(v.x); c[5] = (short)f2bf(v.y);
    c[6] = (short)f2bf(v.z); c[7] = (short)f2bf(v.w);
    return c;
}

// Block-contiguous fragment-ordered W: for (kt, bn), 8 KB chunk of 512 slots.
// slot = n16l*64 + lane; element j: col = bn*128+n16l*16+(lane&15),
// k = kt*32+(lane>>4)*8+j
__global__ void binarize_w(const float* __restrict__ W, unsigned short* __restrict__ Wf) {
    const int g = blockIdx.x * 256 + threadIdx.x;   // 24*6*8*64 = 73728 threads
    const int lane = g & 63;
    const int grp  = g >> 6;
    const int n16l = grp & 7;
    const int bkt  = grp >> 3;
    const int bn   = bkt % NBN;
    const int kt   = bkt / NBN;
    const int col  = bn * 128 + n16l * 16 + (lane & 15);
    const int k0   = kt * 32 + (lane >> 4) * 8;
    const float* src = W + (size_t)col * KDIM + k0;
    s16x8 r;
    #pragma unroll
    for (int j = 0; j < 8; ++j) r[j] = sgnbf(src[j]);
    *(s16x8*)(Wf + (size_t)g * 8) = r;
}

// Barrier that does NOT drain vmcnt (ds ops ordered via lgkmcnt(0)).
#define BAR_NODRAIN() do {                                        \
    asm volatile("s_waitcnt lgkmcnt(0)" ::: "memory");            \
    __builtin_amdgcn_s_barrier();                                 \
    asm volatile("" ::: "memory");                                \
} while (0)

// Scheduling fence: no instruction may cross (pins load-issue points so the
// compiler cannot sink prefetch loads to their use sites — R12 showed it does:
// VGPR_Count 40-64 across R9/R11/R12 vs the ~110 the written schedule needs).
#define SCHED_FENCE() __builtin_amdgcn_sched_barrier(0)

// LDS: fragment-ordered, slot = sub16*64 + lane, 16 B/slot, 512 slots = 8 KB/buf
template<bool PRE>
__global__ __launch_bounds__(256, 4)
void binlin_mfma(const float* __restrict__ X, const float* __restrict__ W,
                 const unsigned short* __restrict__ Wf, float* __restrict__ Out) {
    __shared__ __align__(16) unsigned short As[2][512 * 8];   // 2 x 8 KB
    __shared__ __align__(16) unsigned short Bs[2][512 * 8];   // 2 x 8 KB

    const int bid = blockIdx.x;
    const int cpx = gridDim.x >> 3;                 // 1536 % 8 == 0 -> bijective
    const int swz = (bid & 7) * cpx + (bid >> 3);   // same-XCD chunks; bn fastest
    const int bm = swz / NBN;
    const int bn = swz - bm * NBN;

    const int t    = threadIdx.x;
    const int lane = t & 63;
    const int wid  = t >> 6;
    const int wm   = (wid >> 1) * 64;
    const int wn   = (wid & 1) * 64;
    const int wm16 = (wid >> 1) * 4;
    const int wn16 = (wid & 1) * 4;

    const float* Xb = X + (size_t)bm * BM * KDIM;

    // ---- A staging: thread t reads rows {t>>2, (t>>2)+64}, k-chunk (t&3)*8;
    // adjacent lane quads cover contiguous 128 B per row (proven in R6).
    const int r   = t >> 2;
    const int c8  = (t & 3) * 8;
    const float* Abase = Xb + (size_t)r * KDIM + c8;
    const int sA1 = (r >> 4) * 64 + (r & 15) + 16 * (t & 3);
    const int sA2 = sA1 + 256;

    float4 aR[4];
    s16x8  bR[2];

    auto loadA = [&](int kt) {
        const float* p = Abase + kt * BK;
        aR[0] = *(const float4*)p;
        aR[1] = *(const float4*)(p + 4);
        aR[2] = *(const float4*)(p + (size_t)64 * KDIM);
        aR[3] = *(const float4*)(p + (size_t)64 * KDIM + 4);
    };
    auto writeA = [&](int buf) {
        *(s16x8*)&As[buf][(size_t)sA1 * 8] = cvt8(aR[0], aR[1]);
        *(s16x8*)&As[buf][(size_t)sA2 * 8] = cvt8(aR[2], aR[3]);
    };
    // ---- B staging: thread t owns slots {2t, 2t+1} = contiguous 32 B
    auto loadB = [&](int kt) {
        if constexpr (PRE) {
            const unsigned short* q = Wf + ((size_t)(kt * NBN + bn) * 512 + 2 * t) * 8;
            bR[0] = *(const s16x8*)q;
            bR[1] = *(const s16x8*)(q + 8);
        } else {
            #pragma unroll
            for (int i = 0; i < 2; ++i) {
                const int s    = 2 * t + i;
                const int col  = bn * 128 + (s >> 6) * 16 + (s & 15);
                const int k0   = kt * 32 + ((s >> 4) & 3) * 8;
                const float* wp = W + (size_t)col * KDIM + k0;
                float4 u = *(const float4*)wp;
                float4 v = *(const float4*)(wp + 4);
                s16x8 c;
                c[0] = sgnbf(u.x); c[1] = sgnbf(u.y); c[2] = sgnbf(u.z); c[3] = sgnbf(u.w);
                c[4] = sgnbf(v.x); c[5] = sgnbf(v.y); c[6] = sgnbf(v.z); c[7] = sgnbf(v.w);
                bR[i] = c;
            }
        }
    };
    auto writeB = [&](int buf) {
        *(s16x8*)&Bs[buf][(size_t)(2 * t) * 8]     = bR[0];
        *(s16x8*)&Bs[buf][(size_t)(2 * t + 1) * 8] = bR[1];
    };

    f32x4 acc[4][4] = {};

    // ---- prologue ----
    loadA(0); loadB(0);
    writeA(0); writeB(0);
    BAR_NODRAIN();

    #pragma unroll 2
    for (int kt = 0; kt < NT; ++kt) {
        const int c = kt & 1;
        const bool pf = (kt + 1 < NT);

        // issue-early: next tile's global loads — PINNED here by the fence
        if (pf) { loadA(kt + 1); loadB(kt + 1); }
        SCHED_FENCE();

        // fragments from LDS (lane-linear ds_read_b128)
        s16x8 af[4], bf_[4];
        #pragma unroll
        for (int m = 0; m < 4; ++m)
            af[m] = *(const s16x8*)&As[c][(size_t)((wm16 + m) * 64 + lane) * 8];
        #pragma unroll
        for (int n = 0; n < 4; ++n)
            bf_[n] = *(const s16x8*)&Bs[c][(size_t)((wn16 + n) * 64 + lane) * 8];

        #pragma unroll
        for (int m = 0; m < 4; ++m)
            #pragma unroll
            for (int n = 0; n < 4; ++n)
                acc[m][n] = __builtin_amdgcn_mfma_f32_16x16x32_bf16(
                    af[m], bf_[n], acc[m][n], 0, 0, 0);

        SCHED_FENCE();   // writes may not hoist above the MFMA block
        // write-late into the other buffer, one barrier per iter
        if (pf) {
            writeA(c ^ 1); writeB(c ^ 1);
            BAR_NODRAIN();
        }
    }

    // ---- epilogue: C/D layout col = lane&15, row = (lane>>4)*4 + reg ----
    float* Ob = Out + (size_t)(bm * BM) * NDIM + bn * BN;
    const int lr = lane & 15;
    #pragma unroll
    for (int m = 0; m < 4; ++m) {
        const int row0 = wm + m * 16 + (lane >> 4) * 4;
        #pragma unroll
        for (int n = 0; n < 4; ++n) {
            const int col = wn + n * 16 + lr;
            #pragma unroll
            for (int rr = 0; rr < 4; ++rr)
                Ob[(size_t)(row0 + rr) * NDIM + col] = acc[m][n][rr];
        }
    }
}

extern "C" void kernel_launch(void* const* d_in, const int* in_sizes, int n_in,
                              void* d_out, int out_size, void* d_ws, size_t ws_size,
                              hipStream_t stream) {
    const float* X = (const float*)d_in[0];
    const float* W = (const float*)d_in[1];
    float* Out = (float*)d_out;
    const int M = in_sizes[0] / KDIM;                  // 32768
    const int grid = (M / BM) * NBN;                   // 1536
    const size_t need = (size_t)NDIM * KDIM * sizeof(unsigned short);  // 1.125 MB

    if (ws_size >= need) {
        unsigned short* Wf = (unsigned short*)d_ws;
        binarize_w<<<(NT * NBN * 8 * 64) / 256, 256, 0, stream>>>(W, Wf);
        binlin_mfma<true><<<grid, 256, 0, stream>>>(X, W, Wf, Out);
    } else {
        binlin_mfma<false><<<grid, 256, 0, stream>>>(X, W, nullptr, Out);
    }
}